// Round 1
// baseline (622.768 us; speedup 1.0000x reference)
//
#include <hip/hip_runtime.h>

#define LATENT 40
#define NUM_FLOWS 30

// 8 lanes per batch element. Lane idx (0..7) owns latent components
// [4*idx, 4*idx+4) via float4; lanes 0,1 additionally own [32+4*idx, 32+4*idx+4).
// Dot products reduce across the 8-lane group with __shfl_xor (masks 1,2,4 stay
// within the group). z lives in registers across all 30 flows; w/u rows are
// 160B contiguous so float4 loads are dense and 16B-aligned.
__global__ __launch_bounds__(256) void nf_kernel(
    const float* __restrict__ z_k,   // [B, 40]
    const float* __restrict__ w,     // [B, 1200]
    const float* __restrict__ u,     // [B, 1200]
    const float* __restrict__ bias,  // [B, 30]
    float* __restrict__ out,         // [B*40] z_out then [B] sum_ladj
    int B)
{
    int tid  = blockIdx.x * 256 + threadIdx.x;
    int elem = tid >> 3;
    int idx  = tid & 7;
    if (elem >= B) return;
    const bool has_b = (idx < 2);

    const float4* zp = (const float4*)(z_k + (size_t)elem * LATENT);
    float4 zA = zp[idx];
    float4 zB = make_float4(0.f, 0.f, 0.f, 0.f);
    if (has_b) zB = zp[8 + idx];

    const size_t row = (size_t)elem * (NUM_FLOWS * LATENT);
    const float4* wrow = (const float4*)(w + row);
    const float4* urow = (const float4*)(u + row);
    const float* brow = bias + (size_t)elem * NUM_FLOWS;

    float ladj = 0.f;

    #pragma unroll 2
    for (int i = 0; i < NUM_FLOWS; ++i) {
        const float4* wp = wrow + i * 10;
        const float4* up = urow + i * 10;
        float4 wA = wp[idx];
        float4 uA = up[idx];
        float4 wB = make_float4(0.f, 0.f, 0.f, 0.f);
        float4 uB = make_float4(0.f, 0.f, 0.f, 0.f);
        if (has_b) { wB = wp[8 + idx]; uB = up[8 + idx]; }
        float bi = brow[i];

        float s_wz = wA.x * zA.x + wA.y * zA.y + wA.z * zA.z + wA.w * zA.w
                   + wB.x * zB.x + wB.y * zB.y + wB.z * zB.z + wB.w * zB.w;
        float s_wu = wA.x * uA.x + wA.y * uA.y + wA.z * uA.z + wA.w * uA.w
                   + wB.x * uB.x + wB.y * uB.y + wB.z * uB.z + wB.w * uB.w;

        // reduce both sums across the 8-lane group
        s_wz += __shfl_xor(s_wz, 1); s_wu += __shfl_xor(s_wu, 1);
        s_wz += __shfl_xor(s_wz, 2); s_wu += __shfl_xor(s_wu, 2);
        s_wz += __shfl_xor(s_wz, 4); s_wu += __shfl_xor(s_wu, 4);

        float t = tanhf(s_wz + bi);

        zA.x += uA.x * t; zA.y += uA.y * t; zA.z += uA.z * t; zA.w += uA.w * t;
        zB.x += uB.x * t; zB.y += uB.y * t; zB.z += uB.z * t; zB.w += uB.w * t;

        // sum(psi * u) = (1 - t^2) * sum(w * u)
        float det = 1.0f + (1.0f - t * t) * s_wu;
        ladj += logf(fabsf(det));
    }

    float4* zout = (float4*)(out + (size_t)elem * LATENT);
    zout[idx] = zA;
    if (has_b) zout[8 + idx] = zB;
    if (idx == 0) out[(size_t)B * LATENT + elem] = ladj;
}

extern "C" void kernel_launch(void* const* d_in, const int* in_sizes, int n_in,
                              void* d_out, int out_size, void* d_ws, size_t ws_size,
                              hipStream_t stream) {
    const float* z_k  = (const float*)d_in[0];
    const float* w    = (const float*)d_in[1];
    const float* u    = (const float*)d_in[2];
    const float* bias = (const float*)d_in[3];
    float* out = (float*)d_out;

    int B = in_sizes[0] / LATENT;           // 65536
    int threads = B * 8;                    // 8 lanes per batch element
    int block = 256;
    int grid = (threads + block - 1) / block;
    nf_kernel<<<grid, block, 0, stream>>>(z_k, w, u, bias, out, B);
}

// Round 2
// 608.039 us; speedup vs baseline: 1.0242x; 1.0242x over previous
//
#include <hip/hip_runtime.h>

#define LATENT 40
#define NUM_FLOWS 30
#define PF 4  // prefetch depth (iterations of w/u held in registers)

// 8 lanes per batch element. Lane idx (0..7) owns latent components
// [4*idx, 4*idx+4) (float4) plus component 32+idx (scalar) -> 40 total, no
// divergent loads. Dot products reduce across the 8-lane group with
// __shfl_xor (masks 1,2,4). z stays in registers across all 30 flows.
// Explicit depth-PF rotating prefetch + full unroll forces the compiler to
// keep PF iterations of loads in flight (grouped vmcnt) instead of the
// 32-VGPR load->wait->use serialization seen in R1.
__global__ __launch_bounds__(256) void nf_kernel(
    const float* __restrict__ z_k,   // [B, 40]
    const float* __restrict__ w,     // [B, 1200]
    const float* __restrict__ u,     // [B, 1200]
    const float* __restrict__ bias,  // [B, 30]
    float* __restrict__ out,         // [B*40] z_out then [B] sum_ladj
    int B)
{
    int tid  = blockIdx.x * 256 + threadIdx.x;
    int elem = tid >> 3;
    int idx  = tid & 7;
    if (elem >= B) return;

    const float* zrow = z_k + (size_t)elem * LATENT;
    float4 zA = *(const float4*)(zrow + 4 * idx);   // 16B aligned: 160*elem+16*idx
    float  zt = zrow[32 + idx];

    const float* wrow = w + (size_t)elem * (NUM_FLOWS * LATENT);
    const float* urow = u + (size_t)elem * (NUM_FLOWS * LATENT);

    // Preload all 30 b values for this element: lane idx holds b[4idx..4idx+4)
    // (lane 7 holds only b[28],b[29]). Scalar loads, bounds-guarded tail.
    const float* brow = bias + (size_t)elem * NUM_FLOWS;
    float4 bv = make_float4(0.f, 0.f, 0.f, 0.f);
    {
        int base = 4 * idx;
        bv.x = brow[base];
        bv.y = brow[base + 1];                       // base+1 <= 29, always valid
        if (base + 2 < NUM_FLOWS) bv.z = brow[base + 2];
        if (base + 3 < NUM_FLOWS) bv.w = brow[base + 3];
    }

    // Rotating prefetch buffers (become registers after full unroll).
    float4 wAb[PF], uAb[PF];
    float  wtb[PF], utb[PF];
    #pragma unroll
    for (int i = 0; i < PF; ++i) {
        const float* wp = wrow + i * LATENT;
        const float* up = urow + i * LATENT;
        wAb[i] = *(const float4*)(wp + 4 * idx);
        wtb[i] = wp[32 + idx];
        uAb[i] = *(const float4*)(up + 4 * idx);
        utb[i] = up[32 + idx];
    }

    float ladj = 0.f;

    #pragma unroll
    for (int i = 0; i < NUM_FLOWS; ++i) {
        const int s = i % PF;  // compile-time constant after unroll
        float4 wA = wAb[s];  float wt = wtb[s];
        float4 uA = uAb[s];  float ut = utb[s];

        if (i + PF < NUM_FLOWS) {
            const float* wp = wrow + (i + PF) * LATENT;
            const float* up = urow + (i + PF) * LATENT;
            wAb[s] = *(const float4*)(wp + 4 * idx);
            wtb[s] = wp[32 + idx];
            uAb[s] = *(const float4*)(up + 4 * idx);
            utb[s] = up[32 + idx];
        }

        float s_wz = wA.x * zA.x + wA.y * zA.y + wA.z * zA.z + wA.w * zA.w + wt * zt;
        float s_wu = wA.x * uA.x + wA.y * uA.y + wA.z * uA.z + wA.w * uA.w + wt * ut;

        // Fold b_i in pre-reduction: exactly the owner lane (idx == i>>2) adds
        // component (i&3) of its preloaded float4; after the xor-reduce all 8
        // lanes hold sum(w.z) + b_i.
        if (idx == (i >> 2)) {
            const int c = i & 3;
            s_wz += (c == 0) ? bv.x : (c == 1) ? bv.y : (c == 2) ? bv.z : bv.w;
        }

        s_wz += __shfl_xor(s_wz, 1); s_wu += __shfl_xor(s_wu, 1);
        s_wz += __shfl_xor(s_wz, 2); s_wu += __shfl_xor(s_wu, 2);
        s_wz += __shfl_xor(s_wz, 4); s_wu += __shfl_xor(s_wu, 4);

        float t = tanhf(s_wz);

        zA.x += uA.x * t; zA.y += uA.y * t; zA.z += uA.z * t; zA.w += uA.w * t;
        zt   += ut * t;

        // sum(psi * u) = (1 - t^2) * sum(w * u)
        float det = fmaf(1.0f - t * t, s_wu, 1.0f);
        ladj += logf(fabsf(det));
    }

    float* zout = out + (size_t)elem * LATENT;
    *(float4*)(zout + 4 * idx) = zA;
    zout[32 + idx] = zt;
    if (idx == 0) out[(size_t)B * LATENT + elem] = ladj;
}

extern "C" void kernel_launch(void* const* d_in, const int* in_sizes, int n_in,
                              void* d_out, int out_size, void* d_ws, size_t ws_size,
                              hipStream_t stream) {
    const float* z_k  = (const float*)d_in[0];
    const float* w    = (const float*)d_in[1];
    const float* u    = (const float*)d_in[2];
    const float* bias = (const float*)d_in[3];
    float* out = (float*)d_out;

    int B = in_sizes[0] / LATENT;           // 65536
    int threads = B * 8;                    // 8 lanes per batch element
    int block = 256;
    int grid = (threads + block - 1) / block;
    nf_kernel<<<grid, block, 0, stream>>>(z_k, w, u, bias, out, B);
}